// Round 1
// baseline (355.960 us; speedup 1.0000x reference)
//
#include <hip/hip_runtime.h>

// ---------------------------------------------------------------------------
// Fused CNF ODE func: f = MLP(z,ctx,t), neg_div = -eps^T d(f.eps)/dz
// B=500000, DIM=3, COND=64, IN=68, HID=128.
//
// Round 6: K=32 MFMA + sigma-permuted hidden layout + m-outer acc streaming.
//  - All K>=32 GEMMs use v_mfma_f32_16x16x32_f16 (halves MFMA count and
//    LDS A-fragment reads vs 16x16x16).
//  - Hidden-feature permutation sigma baked into LDS weights so two adjacent
//    m-tile outputs concatenate directly into the next layer's B8 fragment.
//  - m-outer/kk-inner: one acc pair live (8 regs) instead of acc[8][2] (64).
//    f fused into L3 epilogue (h3 streamed in pairs); gz fused into bwd2
//    (u1 never materialized). Peak live ~145 VGPR.
//  - 768-thread block (12 waves/CU, 3 waves/SIMD) — occupancy 8->12 waves/CU.
//  - LDS layout/offsets identical to R5; only contents permuted. 161328 B.
// ---------------------------------------------------------------------------

#define B_N    500000
#define NT32   15625          // 500000 / 32 exact
#define GRID   256
#define WPB    12             // waves per block (768 threads)
#define NSTR   (GRID * WPB)   // 3072 wave slots

// LDS/ws f16-element offsets (identical layout in ws and LDS)
#define L_WFIN   0            // [128][68]  W_in^T (k:0..63 ctx,64..66 z,67 t)
#define L_WF1    8704         // [128][132] W_h1^T, K sigma-permuted (fwd L2 A)
#define L_WF2    25600        // [128][132] W_h2^T, K sigma-permuted (fwd L3 A)
#define L_WB2    42496        // [128][132] W_h2,   K sigma-permuted (bwd3 A)
#define L_WB1    59392        // [128][132] W_h1,   K sigma-permuted (bwd2 A)
#define L_WOUTP  76288        // [128][4]   W_out rows (u3pre A, k<3 real)
#define L_WOUTT  76800        // [3][132]   W_out^T, K sigma-permuted (f A)
#define L_WIN3   77196        // [3][132]   W_in rows 0..2, K sigma-perm (gz A)
#define L_F16END 77592
#define N_BIAS   384                         // f32 b_in|b_h1|b_h2
#define PREP_N   (L_F16END + N_BIAS)         // 77976 work items
#define BIAS_BYTE   155184                   // L_F16END*2
#define OUTST_BYTE  156720                   // BIAS_BYTE + 1536
#define LDS_BYTES   161328                   // OUTST_BYTE + 12*96*4
#define COPY16      9795                     // 156720/16 uint4 ws->LDS

typedef _Float16 f16x4 __attribute__((ext_vector_type(4)));
typedef _Float16 f16x8 __attribute__((ext_vector_type(8)));
typedef float    f32x4 __attribute__((ext_vector_type(4)));

union U4 { f16x4 v; _Float16 e[4]; uint2 d; };
union U8 { f16x8 v; f16x4 h[2]; _Float16 e[8]; uint2 d2[2]; };

static __device__ inline f16x4 lds_a4(const _Float16* p) {
    U4 u; u.d = *reinterpret_cast<const uint2*>(p); return u.v;
}
static __device__ inline f16x8 lds_a8(const _Float16* p) {
    U8 u;
    u.d2[0] = *reinterpret_cast<const uint2*>(p);
    u.d2[1] = *reinterpret_cast<const uint2*>(p + 4);
    return u.v;
}

#define MFMA16(a, b, c) __builtin_amdgcn_mfma_f32_16x16x16f16((a), (b), (c), 0, 0, 0)
#define MFMA32(a, b, c) __builtin_amdgcn_mfma_f32_16x16x32_f16((a), (b), (c), 0, 0, 0)

static __device__ inline float ftanh(float x) {
    float e = __expf(2.f * x);
    return 1.f - 2.f * __builtin_amdgcn_rcpf(e + 1.f);
}

// sigma: k-position p -> natural feature index, for K=32 MFMA B-frag packing.
// p = 32a + 8q + 4c + i  ->  32a + 16c + 4q + i
static __device__ inline int sig(int p) {
    return (p & ~31) | ((p & 4) << 2) | ((p >> 1) & 12) | (p & 3);
}

// ---------------------------------------------------------------------------
// Prep: fp32 weights -> f16 ws arrays + f32 biases (K dims sigma-permuted)
// ---------------------------------------------------------------------------
__global__ void prep_kernel(const float* __restrict__ W_in,
                            const float* __restrict__ W_h1,
                            const float* __restrict__ W_h2,
                            const float* __restrict__ W_out,
                            const float* __restrict__ b_in,
                            const float* __restrict__ b_h1,
                            const float* __restrict__ b_h2,
                            _Float16* __restrict__ ws) {
    int i = blockIdx.x * 256 + threadIdx.x;
    if (i >= PREP_N) return;
    if (i >= L_F16END) {                        // bias f32 region
        int bi = i - L_F16END;
        float* bp = reinterpret_cast<float*>(ws + L_F16END);
        bp[bi] = (bi < 128) ? b_in[bi] : (bi < 256) ? b_h1[bi - 128]
                                                    : b_h2[bi - 256];
        return;
    }
    float v = 0.f;
    if (i < L_WF1) {                            // WFIN [128][68] (natural K)
        int n = i / 68, k = i - n * 68;
        if      (k < 64)  v = W_in[(3 + k) * 128 + n];
        else if (k < 67)  v = W_in[(k - 64) * 128 + n];
        else              v = W_in[67 * 128 + n];
    } else if (i < L_WF2) {                     // WF1 = W_h1^T, K sigma
        int j = i - L_WF1; int n = j / 132, a = j - n * 132;
        if (a < 128) v = W_h1[sig(a) * 128 + n];
    } else if (i < L_WB2) {                     // WF2 = W_h2^T, K sigma
        int j = i - L_WF2; int n = j / 132, a = j - n * 132;
        if (a < 128) v = W_h2[sig(a) * 128 + n];
    } else if (i < L_WB1) {                     // WB2 = W_h2, K sigma
        int j = i - L_WB2; int r = j / 132, b = j - r * 132;
        if (b < 128) v = W_h2[r * 128 + sig(b)];
    } else if (i < L_WOUTP) {                   // WB1 = W_h1, K sigma
        int j = i - L_WB1; int r = j / 132, b = j - r * 132;
        if (b < 128) v = W_h1[r * 128 + sig(b)];
    } else if (i < L_WOUTT) {                   // WOUTP [128][4] (natural)
        int j = i - L_WOUTP; int n = j >> 2, k = j & 3;
        if (k < 3) v = W_out[n * 3 + k];
    } else if (i < L_WIN3) {                    // WOUTT [3][132], K sigma
        int j = i - L_WOUTT; int d = j / 132, n = j - d * 132;
        if (n < 128) v = W_out[sig(n) * 3 + d];
    } else {                                    // WIN3 [3][132], K sigma
        int j = i - L_WIN3; int d = j / 132, a = j - d * 132;
        if (a < 128) v = W_in[d * 128 + sig(a)];
    }
    ws[i] = (_Float16)v;
}

// ---------------------------------------------------------------------------
// Main fused kernel — K=32 MFMA, m-outer streaming, no main-loop barriers
// ---------------------------------------------------------------------------
__global__ __launch_bounds__(768, 3) void fused_kernel(
        const float* __restrict__ t_p,  const float* __restrict__ z,
        const float* __restrict__ ctx,  const float* __restrict__ eps,
        const float* __restrict__ b_out, const float* __restrict__ os_p,
        const _Float16* __restrict__ ws, float* __restrict__ out) {
    extern __shared__ _Float16 smem[];
    const int tid  = threadIdx.x;
    const int wave = tid >> 6;
    const int lane = tid & 63;
    const int l15  = lane & 15;
    const int q    = lane >> 4;

    // stage weights + biases ws -> LDS (one contiguous copy)
    {
        const uint4* src = reinterpret_cast<const uint4*>(ws);
        uint4* dst = reinterpret_cast<uint4*>(smem);
        for (int i = tid; i < COPY16; i += 768) dst[i] = src[i];
    }
    __syncthreads();   // the only block barrier

    const _Float16* WFIN  = smem + L_WFIN;
    const _Float16* WF1   = smem + L_WF1;
    const _Float16* WF2   = smem + L_WF2;
    const _Float16* WB2   = smem + L_WB2;
    const _Float16* WB1   = smem + L_WB1;
    const _Float16* WOUTP = smem + L_WOUTP;
    const _Float16* WOUTT = smem + L_WOUTT;
    const _Float16* WIN3  = smem + L_WIN3;
    const float* biasf =
        reinterpret_cast<const float*>(reinterpret_cast<char*>(smem) + BIAS_BYTE);
    float* outst =
        reinterpret_cast<float*>(reinterpret_cast<char*>(smem) + OUTST_BYTE)
        + wave * 96;

    const float tval = t_p[0];
    const float os   = os_p[0];
    const float bo0 = b_out[0], bo1 = b_out[1], bo2 = b_out[2];
    float* out_f  = out;
    float* out_nd = out + (size_t)B_N * 3;

    const f32x4 zero4 = {0.f, 0.f, 0.f, 0.f};

    for (int t = blockIdx.x + wave * GRID; t < NT32; t += NSTR) {
        const int gb = t * 32;

        // ---- eps fragments (q==0 lanes hold batch row gb+16c+l15)
        U4 epsb[2];
        float ee[2][3];
        #pragma unroll
        for (int c = 0; c < 2; ++c) {
            epsb[c].d.x = 0u; epsb[c].d.y = 0u;
            ee[c][0] = ee[c][1] = ee[c][2] = 0.f;
            if (q == 0) {
                const float* ep = eps + (size_t)(gb + 16 * c + l15) * 3;
                ee[c][0] = ep[0]; ee[c][1] = ep[1]; ee[c][2] = ep[2];
                epsb[c].e[0] = (_Float16)ee[c][0];
                epsb[c].e[1] = (_Float16)ee[c][1];
                epsb[c].e[2] = (_Float16)ee[c][2];
            }
        }

        // ---- ctx B-frags (K=32 chunks a=0,1), z/t B-frag (K=16)
        U8 cb[2][2];
        #pragma unroll
        for (int a = 0; a < 2; ++a)
            #pragma unroll
            for (int c = 0; c < 2; ++c) {
                const float* cp = ctx + (size_t)(gb + 16 * c + l15) * 64
                                  + a * 32 + 8 * q;
                const float4 v0 = *reinterpret_cast<const float4*>(cp);
                const float4 v1 = *reinterpret_cast<const float4*>(cp + 4);
                cb[a][c].e[0] = (_Float16)v0.x; cb[a][c].e[1] = (_Float16)v0.y;
                cb[a][c].e[2] = (_Float16)v0.z; cb[a][c].e[3] = (_Float16)v0.w;
                cb[a][c].e[4] = (_Float16)v1.x; cb[a][c].e[5] = (_Float16)v1.y;
                cb[a][c].e[6] = (_Float16)v1.z; cb[a][c].e[7] = (_Float16)v1.w;
            }
        U4 bz[2];
        #pragma unroll
        for (int c = 0; c < 2; ++c) {
            bz[c].d.x = 0u; bz[c].d.y = 0u;
            if (q == 0) {
                const float* zp = z + (size_t)(gb + 16 * c + l15) * 3;
                bz[c].e[0] = (_Float16)zp[0]; bz[c].e[1] = (_Float16)zp[1];
                bz[c].e[2] = (_Float16)zp[2]; bz[c].e[3] = (_Float16)tval;
            }
        }

        // ================= L1: X1 = W_in^T @ inp^T  (K=80) =================
        // state U8 packing: h[a][c].e[(m&1)*4+i] = feature 16m+4q+i, m=2a+sub
        U8 h1p[4][2];
        #pragma unroll
        for (int m = 0; m < 8; ++m) {
            f32x4 a0 = zero4, a1 = zero4;
            #pragma unroll
            for (int a = 0; a < 2; ++a) {
                f16x8 A = lds_a8(WFIN + (16 * m + l15) * 68 + a * 32 + 8 * q);
                a0 = MFMA32(A, cb[a][0].v, a0);
                a1 = MFMA32(A, cb[a][1].v, a1);
            }
            {   // z+t chunk (q>=1 lanes read neighbor-row garbage * 0)
                f16x4 A4 = lds_a4(WFIN + (16 * m + l15) * 68 + 64 + 4 * q);
                a0 = MFMA16(A4, bz[0].v, a0);
                a1 = MFMA16(A4, bz[1].v, a1);
            }
            const float4 bb = *reinterpret_cast<const float4*>(
                biasf + 0 + 16 * m + 4 * q);
            #pragma unroll
            for (int c = 0; c < 2; ++c) {
                const f32x4 ac = c ? a1 : a0;
                h1p[m >> 1][c].e[(m & 1) * 4 + 0] = (_Float16)ftanh(ac[0] + bb.x);
                h1p[m >> 1][c].e[(m & 1) * 4 + 1] = (_Float16)ftanh(ac[1] + bb.y);
                h1p[m >> 1][c].e[(m & 1) * 4 + 2] = (_Float16)ftanh(ac[2] + bb.z);
                h1p[m >> 1][c].e[(m & 1) * 4 + 3] = (_Float16)ftanh(ac[3] + bb.w);
            }
        }

        // ================= L2: H2 = tanh(W_h1^T @ H1 + b1) =================
        U8 h2p[4][2];
        #pragma unroll
        for (int m = 0; m < 8; ++m) {
            f32x4 a0 = zero4, a1 = zero4;
            #pragma unroll
            for (int a = 0; a < 4; ++a) {
                f16x8 A = lds_a8(WF1 + (16 * m + l15) * 132 + a * 32 + 8 * q);
                a0 = MFMA32(A, h1p[a][0].v, a0);
                a1 = MFMA32(A, h1p[a][1].v, a1);
            }
            const float4 bb = *reinterpret_cast<const float4*>(
                biasf + 128 + 16 * m + 4 * q);
            #pragma unroll
            for (int c = 0; c < 2; ++c) {
                const f32x4 ac = c ? a1 : a0;
                h2p[m >> 1][c].e[(m & 1) * 4 + 0] = (_Float16)ftanh(ac[0] + bb.x);
                h2p[m >> 1][c].e[(m & 1) * 4 + 1] = (_Float16)ftanh(ac[1] + bb.y);
                h2p[m >> 1][c].e[(m & 1) * 4 + 2] = (_Float16)ftanh(ac[2] + bb.z);
                h2p[m >> 1][c].e[(m & 1) * 4 + 3] = (_Float16)ftanh(ac[3] + bb.w);
            }
        }

        // ====== L3 + u3pre + fused f: stream h3 in m-pairs into f-acc ======
        U8 u3p[4][2];
        f32x4 f0 = zero4, f1 = zero4;
        #pragma unroll
        for (int mp = 0; mp < 4; ++mp) {
            U8 h3pr[2];
            #pragma unroll
            for (int sub = 0; sub < 2; ++sub) {
                const int m = 2 * mp + sub;
                f32x4 a0 = zero4, a1 = zero4;
                #pragma unroll
                for (int a = 0; a < 4; ++a) {
                    f16x8 A = lds_a8(WF2 + (16 * m + l15) * 132 + a * 32 + 8 * q);
                    a0 = MFMA32(A, h2p[a][0].v, a0);
                    a1 = MFMA32(A, h2p[a][1].v, a1);
                }
                f16x4 a3 = lds_a4(WOUTP + (16 * m + l15) * 4 + 4 * q);
                f32x4 up0 = MFMA16(a3, epsb[0].v, zero4);
                f32x4 up1 = MFMA16(a3, epsb[1].v, zero4);
                const float4 bb = *reinterpret_cast<const float4*>(
                    biasf + 256 + 16 * m + 4 * q);
                #pragma unroll
                for (int c = 0; c < 2; ++c) {
                    const f32x4 ac = c ? a1 : a0;
                    const f32x4 uc = c ? up1 : up0;
                    #pragma unroll
                    for (int i = 0; i < 4; ++i) {
                        float bi = (i == 0) ? bb.x : (i == 1) ? bb.y
                                  : (i == 2) ? bb.z : bb.w;
                        float h = ftanh(ac[i] + bi);
                        h3pr[c].e[sub * 4 + i] = (_Float16)h;
                        u3p[mp][c].e[sub * 4 + i] =
                            (_Float16)(os * uc[i] * (1.f - h * h));
                    }
                }
            }
            f16x8 Af = lds_a8(WOUTT + l15 * 132 + mp * 32 + 8 * q);
            f0 = MFMA32(Af, h3pr[0].v, f0);
            f1 = MFMA32(Af, h3pr[1].v, f1);
        }
        // stage f to LDS now (frees f0/f1 before bwd phase)
        if (q == 0) {
            outst[(0 * 16 + l15) * 3 + 0] = (f0[0] + bo0) * os;
            outst[(0 * 16 + l15) * 3 + 1] = (f0[1] + bo1) * os;
            outst[(0 * 16 + l15) * 3 + 2] = (f0[2] + bo2) * os;
            outst[(1 * 16 + l15) * 3 + 0] = (f1[0] + bo0) * os;
            outst[(1 * 16 + l15) * 3 + 1] = (f1[1] + bo1) * os;
            outst[(1 * 16 + l15) * 3 + 2] = (f1[2] + bo2) * os;
        }

        // ================= bwd3: U2 = (W_h2 @ U3) * (1-h2^2) ===============
        #pragma unroll
        for (int m = 0; m < 8; ++m) {
            f32x4 a0 = zero4, a1 = zero4;
            #pragma unroll
            for (int a = 0; a < 4; ++a) {
                f16x8 A = lds_a8(WB2 + (16 * m + l15) * 132 + a * 32 + 8 * q);
                a0 = MFMA32(A, u3p[a][0].v, a0);
                a1 = MFMA32(A, u3p[a][1].v, a1);
            }
            #pragma unroll
            for (int c = 0; c < 2; ++c) {
                const f32x4 ac = c ? a1 : a0;
                #pragma unroll
                for (int i = 0; i < 4; ++i) {
                    float h = (float)h2p[m >> 1][c].e[(m & 1) * 4 + i];
                    h2p[m >> 1][c].e[(m & 1) * 4 + i] =
                        (_Float16)(ac[i] * (1.f - h * h));   // h2p becomes u2
                }
            }
        }

        // ==== bwd2 + fused gz: U1 streamed in m-pairs into gz accumulator ==
        f32x4 g0 = zero4, g1 = zero4;
        #pragma unroll
        for (int mp = 0; mp < 4; ++mp) {
            U8 u1pr[2];
            #pragma unroll
            for (int sub = 0; sub < 2; ++sub) {
                const int m = 2 * mp + sub;
                f32x4 a0 = zero4, a1 = zero4;
                #pragma unroll
                for (int a = 0; a < 4; ++a) {
                    f16x8 A = lds_a8(WB1 + (16 * m + l15) * 132 + a * 32 + 8 * q);
                    a0 = MFMA32(A, h2p[a][0].v, a0);
                    a1 = MFMA32(A, h2p[a][1].v, a1);
                }
                #pragma unroll
                for (int c = 0; c < 2; ++c) {
                    const f32x4 ac = c ? a1 : a0;
                    #pragma unroll
                    for (int i = 0; i < 4; ++i) {
                        float h = (float)h1p[m >> 1][c].e[(m & 1) * 4 + i];
                        u1pr[c].e[sub * 4 + i] =
                            (_Float16)(ac[i] * (1.f - h * h));
                    }
                }
            }
            f16x8 Ag = lds_a8(WIN3 + l15 * 132 + mp * 32 + 8 * q);
            g0 = MFMA32(Ag, u1pr[0].v, g0);
            g1 = MFMA32(Ag, u1pr[1].v, g1);
        }
        if (q == 0) {   // 16-lane coalesced dword stores, direct
            out_nd[gb + l15] =
                -(g0[0] * ee[0][0] + g0[1] * ee[0][1] + g0[2] * ee[0][2]);
            out_nd[gb + 16 + l15] =
                -(g1[0] * ee[1][0] + g1[1] * ee[1][1] + g1[2] * ee[1][2]);
        }

        // ---- dense f stores from LDS staging (in-order same-wave DS)
        if (lane < 24) {
            float4 v = *reinterpret_cast<const float4*>(outst + lane * 4);
            *reinterpret_cast<float4*>(out_f + (size_t)gb * 3 + lane * 4) = v;
        }
    }
}

extern "C" void kernel_launch(void* const* d_in, const int* in_sizes, int n_in,
                              void* d_out, int out_size, void* d_ws, size_t ws_size,
                              hipStream_t stream) {
    const float* t_p   = (const float*)d_in[0];
    const float* z     = (const float*)d_in[1];
    // d_in[2] = logp (unused)
    const float* ctx   = (const float*)d_in[3];
    const float* eps   = (const float*)d_in[4];
    const float* W_in  = (const float*)d_in[5];
    const float* b_in  = (const float*)d_in[6];
    const float* W_h1  = (const float*)d_in[7];
    const float* b_h1  = (const float*)d_in[8];
    const float* W_h2  = (const float*)d_in[9];
    const float* b_h2  = (const float*)d_in[10];
    const float* W_out = (const float*)d_in[11];
    const float* b_out = (const float*)d_in[12];
    const float* os_p  = (const float*)d_in[13];
    _Float16* ws = (_Float16*)d_ws;
    float* out = (float*)d_out;

    static bool attr_set = false;
    if (!attr_set) {
        (void)hipFuncSetAttribute((const void*)fused_kernel,
                                  hipFuncAttributeMaxDynamicSharedMemorySize,
                                  LDS_BYTES);
        attr_set = true;
    }

    prep_kernel<<<(PREP_N + 255) / 256, 256, 0, stream>>>(
        W_in, W_h1, W_h2, W_out, b_in, b_h1, b_h2, ws);
    fused_kernel<<<GRID, 768, LDS_BYTES, stream>>>(
        t_p, z, ctx, eps, b_out, os_p, ws, out);
}

// Round 2
// 310.303 us; speedup vs baseline: 1.1471x; 1.1471x over previous
//
#include <hip/hip_runtime.h>

// ---------------------------------------------------------------------------
// Fused CNF ODE func: f = MLP(z,ctx,t), neg_div = -eps^T d(f.eps)/dz
// B=500000, DIM=3, COND=64, IN=68, HID=128.
//
// Round 7: R6's K=32 MFMA + sigma layout, de-spilled.
//  - Back to 512 thr / __launch_bounds__(512,1): VGPR cap 256 (R5-proven
//    no-spill regime). R6's 768-thr/170-cap forced wholesale scratch
//    demotion of the state arrays (VGPR 84 + 350MB spill traffic).
//  - NO unions anywhere: pure ext_vector state with compile-time-constant
//    subscripts only (SROA-safe, rule #20).
//  - All K>=32 GEMMs on v_mfma_f32_16x16x32_f16; sigma permutation baked
//    into LDS weights so adjacent m-tile outputs concatenate into the next
//    layer's B8 fragment with zero repacking (harness-verified in R6).
// ---------------------------------------------------------------------------

#define B_N    500000
#define NT32   15625          // 500000 / 32 exact
#define GRID   256
#define WPB    8              // waves per block (512 threads)
#define NSTR   (GRID * WPB)   // 2048 wave slots

// LDS/ws f16-element offsets (identical layout in ws and LDS)
#define L_WFIN   0            // [128][68]  W_in^T (k:0..63 ctx,64..66 z,67 t)
#define L_WF1    8704         // [128][132] W_h1^T, K sigma-permuted (fwd L2 A)
#define L_WF2    25600        // [128][132] W_h2^T, K sigma-permuted (fwd L3 A)
#define L_WB2    42496        // [128][132] W_h2,   K sigma-permuted (bwd3 A)
#define L_WB1    59392        // [128][132] W_h1,   K sigma-permuted (bwd2 A)
#define L_WOUTP  76288        // [128][4]   W_out rows (u3pre A, k<3 real)
#define L_WOUTT  76800        // [3][132]   W_out^T, K sigma-permuted (f A)
#define L_WIN3   77196        // [3][132]   W_in rows 0..2, K sigma-perm (gz A)
#define L_F16END 77592
#define N_BIAS   384                         // f32 b_in|b_h1|b_h2
#define PREP_N   (L_F16END + N_BIAS)         // 77976 work items
#define BIAS_BYTE   155184                   // L_F16END*2
#define OUTST_BYTE  156720                   // BIAS_BYTE + 1536
#define LDS_BYTES   159792                   // OUTST_BYTE + 8*96*4
#define COPY16      9795                     // 156720/16 uint4 ws->LDS

typedef _Float16 f16x4 __attribute__((ext_vector_type(4)));
typedef _Float16 f16x8 __attribute__((ext_vector_type(8)));
typedef float    f32x4 __attribute__((ext_vector_type(4)));

static __device__ inline f16x4 lds_a4(const _Float16* p) {
    return *reinterpret_cast<const f16x4*>(p);          // 8B-aligned ds_read_b64
}
static __device__ inline f16x8 lds_a8(const _Float16* p) {
    f16x4 lo = *reinterpret_cast<const f16x4*>(p);      // rows are 8B-aligned,
    f16x4 hi = *reinterpret_cast<const f16x4*>(p + 4);  // not 16B -> two b64
    return __builtin_shufflevector(lo, hi, 0, 1, 2, 3, 4, 5, 6, 7);
}

#define MFMA16(a, b, c) __builtin_amdgcn_mfma_f32_16x16x16f16((a), (b), (c), 0, 0, 0)
#define MFMA32(a, b, c) __builtin_amdgcn_mfma_f32_16x16x32_f16((a), (b), (c), 0, 0, 0)

static __device__ inline float ftanh(float x) {
    float e = __expf(2.f * x);
    return 1.f - 2.f * __builtin_amdgcn_rcpf(e + 1.f);
}

// tanh+cvt insert of one f32x4 into elements [sub*4 .. sub*4+3] of dst
#define TANH4(dst, sub, acv, bb)                               \
    dst[(sub) * 4 + 0] = (_Float16)ftanh((acv)[0] + (bb).x);   \
    dst[(sub) * 4 + 1] = (_Float16)ftanh((acv)[1] + (bb).y);   \
    dst[(sub) * 4 + 2] = (_Float16)ftanh((acv)[2] + (bb).z);   \
    dst[(sub) * 4 + 3] = (_Float16)ftanh((acv)[3] + (bb).w);

// sigma: k-position p -> natural feature index, for K=32 MFMA B-frag packing.
// p = 32a + 8q + 4c + i  ->  32a + 16c + 4q + i
static __device__ inline int sig(int p) {
    return (p & ~31) | ((p & 4) << 2) | ((p >> 1) & 12) | (p & 3);
}

// ---------------------------------------------------------------------------
// Prep: fp32 weights -> f16 ws arrays + f32 biases (K dims sigma-permuted)
// ---------------------------------------------------------------------------
__global__ void prep_kernel(const float* __restrict__ W_in,
                            const float* __restrict__ W_h1,
                            const float* __restrict__ W_h2,
                            const float* __restrict__ W_out,
                            const float* __restrict__ b_in,
                            const float* __restrict__ b_h1,
                            const float* __restrict__ b_h2,
                            _Float16* __restrict__ ws) {
    int i = blockIdx.x * 256 + threadIdx.x;
    if (i >= PREP_N) return;
    if (i >= L_F16END) {                        // bias f32 region
        int bi = i - L_F16END;
        float* bp = reinterpret_cast<float*>(ws + L_F16END);
        bp[bi] = (bi < 128) ? b_in[bi] : (bi < 256) ? b_h1[bi - 128]
                                                    : b_h2[bi - 256];
        return;
    }
    float v = 0.f;
    if (i < L_WF1) {                            // WFIN [128][68] (natural K)
        int n = i / 68, k = i - n * 68;
        if      (k < 64)  v = W_in[(3 + k) * 128 + n];
        else if (k < 67)  v = W_in[(k - 64) * 128 + n];
        else              v = W_in[67 * 128 + n];
    } else if (i < L_WF2) {                     // WF1 = W_h1^T, K sigma
        int j = i - L_WF1; int n = j / 132, a = j - n * 132;
        if (a < 128) v = W_h1[sig(a) * 128 + n];
    } else if (i < L_WB2) {                     // WF2 = W_h2^T, K sigma
        int j = i - L_WF2; int n = j / 132, a = j - n * 132;
        if (a < 128) v = W_h2[sig(a) * 128 + n];
    } else if (i < L_WB1) {                     // WB2 = W_h2, K sigma
        int j = i - L_WB2; int r = j / 132, b = j - r * 132;
        if (b < 128) v = W_h2[r * 128 + sig(b)];
    } else if (i < L_WOUTP) {                   // WB1 = W_h1, K sigma
        int j = i - L_WB1; int r = j / 132, b = j - r * 132;
        if (b < 128) v = W_h1[r * 128 + sig(b)];
    } else if (i < L_WOUTT) {                   // WOUTP [128][4] (natural)
        int j = i - L_WOUTP; int n = j >> 2, k = j & 3;
        if (k < 3) v = W_out[n * 3 + k];
    } else if (i < L_WIN3) {                    // WOUTT [3][132], K sigma
        int j = i - L_WOUTT; int d = j / 132, n = j - d * 132;
        if (n < 128) v = W_out[sig(n) * 3 + d];
    } else {                                    // WIN3 [3][132], K sigma
        int j = i - L_WIN3; int d = j / 132, a = j - d * 132;
        if (a < 128) v = W_in[d * 128 + sig(a)];
    }
    ws[i] = (_Float16)v;
}

// ---------------------------------------------------------------------------
// Main fused kernel — K=32 MFMA, m-outer streaming, no main-loop barriers
// ---------------------------------------------------------------------------
__global__ __launch_bounds__(512, 1) void fused_kernel(
        const float* __restrict__ t_p,  const float* __restrict__ z,
        const float* __restrict__ ctx,  const float* __restrict__ eps,
        const float* __restrict__ b_out, const float* __restrict__ os_p,
        const _Float16* __restrict__ ws, float* __restrict__ out) {
    extern __shared__ _Float16 smem[];
    const int tid  = threadIdx.x;
    const int wave = tid >> 6;
    const int lane = tid & 63;
    const int l15  = lane & 15;
    const int q    = lane >> 4;

    // stage weights + biases ws -> LDS (one contiguous copy)
    {
        const uint4* src = reinterpret_cast<const uint4*>(ws);
        uint4* dst = reinterpret_cast<uint4*>(smem);
        for (int i = tid; i < COPY16; i += 512) dst[i] = src[i];
    }
    __syncthreads();   // the only block barrier

    const _Float16* WFIN  = smem + L_WFIN;
    const _Float16* WF1   = smem + L_WF1;
    const _Float16* WF2   = smem + L_WF2;
    const _Float16* WB2   = smem + L_WB2;
    const _Float16* WB1   = smem + L_WB1;
    const _Float16* WOUTP = smem + L_WOUTP;
    const _Float16* WOUTT = smem + L_WOUTT;
    const _Float16* WIN3  = smem + L_WIN3;
    const float* biasf =
        reinterpret_cast<const float*>(reinterpret_cast<char*>(smem) + BIAS_BYTE);
    float* outst =
        reinterpret_cast<float*>(reinterpret_cast<char*>(smem) + OUTST_BYTE)
        + wave * 96;

    const float tval = t_p[0];
    const float os   = os_p[0];
    const float bo0 = b_out[0], bo1 = b_out[1], bo2 = b_out[2];
    float* out_f  = out;
    float* out_nd = out + (size_t)B_N * 3;

    const f32x4 zero4 = {0.f, 0.f, 0.f, 0.f};
    const _Float16 hz = (_Float16)0.f;

    for (int t = blockIdx.x * WPB + wave; t < NT32; t += NSTR) {
        const int gb = t * 32;

        // ---- eps fragments (q==0 lanes hold batch row gb+16c+l15)
        f16x4 epsb[2];
        float ee[2][3];
        #pragma unroll
        for (int c = 0; c < 2; ++c) {
            f16x4 ev = {hz, hz, hz, hz};
            ee[c][0] = ee[c][1] = ee[c][2] = 0.f;
            if (q == 0) {
                const float* ep = eps + (size_t)(gb + 16 * c + l15) * 3;
                ee[c][0] = ep[0]; ee[c][1] = ep[1]; ee[c][2] = ep[2];
                ev[0] = (_Float16)ee[c][0];
                ev[1] = (_Float16)ee[c][1];
                ev[2] = (_Float16)ee[c][2];
            }
            epsb[c] = ev;
        }

        // ---- ctx B-frags (K=32 chunks a=0,1), z/t B-frag (K=16)
        f16x8 cb[2][2];
        #pragma unroll
        for (int a = 0; a < 2; ++a)
            #pragma unroll
            for (int c = 0; c < 2; ++c) {
                const float* cp = ctx + (size_t)(gb + 16 * c + l15) * 64
                                  + a * 32 + 8 * q;
                const float4 v0 = *reinterpret_cast<const float4*>(cp);
                const float4 v1 = *reinterpret_cast<const float4*>(cp + 4);
                f16x8 cv;
                cv[0] = (_Float16)v0.x; cv[1] = (_Float16)v0.y;
                cv[2] = (_Float16)v0.z; cv[3] = (_Float16)v0.w;
                cv[4] = (_Float16)v1.x; cv[5] = (_Float16)v1.y;
                cv[6] = (_Float16)v1.z; cv[7] = (_Float16)v1.w;
                cb[a][c] = cv;
            }
        f16x4 bz[2];
        #pragma unroll
        for (int c = 0; c < 2; ++c) {
            f16x4 zv = {hz, hz, hz, hz};
            if (q == 0) {
                const float* zp = z + (size_t)(gb + 16 * c + l15) * 3;
                zv[0] = (_Float16)zp[0]; zv[1] = (_Float16)zp[1];
                zv[2] = (_Float16)zp[2]; zv[3] = (_Float16)tval;
            }
            bz[c] = zv;
        }

        // ================= L1: X1 = W_in^T @ inp^T  (K=80) =================
        // state packing: h1p[m>>1][c][(m&1)*4+i] = feature 16m+4q+i
        f16x8 h1p[4][2];
        #pragma unroll
        for (int m = 0; m < 8; ++m) {
            f32x4 a0 = zero4, a1 = zero4;
            #pragma unroll
            for (int a = 0; a < 2; ++a) {
                f16x8 A = lds_a8(WFIN + (16 * m + l15) * 68 + a * 32 + 8 * q);
                a0 = MFMA32(A, cb[a][0], a0);
                a1 = MFMA32(A, cb[a][1], a1);
            }
            {   // z+t chunk (q>=1 lanes read neighbor-row garbage * 0)
                f16x4 A4 = lds_a4(WFIN + (16 * m + l15) * 68 + 64 + 4 * q);
                a0 = MFMA16(A4, bz[0], a0);
                a1 = MFMA16(A4, bz[1], a1);
            }
            const float4 bb = *reinterpret_cast<const float4*>(
                biasf + 0 + 16 * m + 4 * q);
            TANH4(h1p[m >> 1][0], m & 1, a0, bb);
            TANH4(h1p[m >> 1][1], m & 1, a1, bb);
        }

        // ================= L2: H2 = tanh(W_h1^T @ H1 + b1) =================
        f16x8 h2p[4][2];
        #pragma unroll
        for (int m = 0; m < 8; ++m) {
            f32x4 a0 = zero4, a1 = zero4;
            #pragma unroll
            for (int a = 0; a < 4; ++a) {
                f16x8 A = lds_a8(WF1 + (16 * m + l15) * 132 + a * 32 + 8 * q);
                a0 = MFMA32(A, h1p[a][0], a0);
                a1 = MFMA32(A, h1p[a][1], a1);
            }
            const float4 bb = *reinterpret_cast<const float4*>(
                biasf + 128 + 16 * m + 4 * q);
            TANH4(h2p[m >> 1][0], m & 1, a0, bb);
            TANH4(h2p[m >> 1][1], m & 1, a1, bb);
        }

        // ====== L3 + u3pre + fused f: stream h3 in m-pairs into f-acc ======
        f16x8 u3p[4][2];
        f32x4 f0 = zero4, f1 = zero4;
        #pragma unroll
        for (int mp = 0; mp < 4; ++mp) {
            f16x8 h3p0, h3p1;
            #pragma unroll
            for (int sub = 0; sub < 2; ++sub) {
                const int m = 2 * mp + sub;
                f32x4 a0 = zero4, a1 = zero4;
                #pragma unroll
                for (int a = 0; a < 4; ++a) {
                    f16x8 A = lds_a8(WF2 + (16 * m + l15) * 132 + a * 32 + 8 * q);
                    a0 = MFMA32(A, h2p[a][0], a0);
                    a1 = MFMA32(A, h2p[a][1], a1);
                }
                f16x4 a3 = lds_a4(WOUTP + (16 * m + l15) * 4 + 4 * q);
                f32x4 up0 = MFMA16(a3, epsb[0], zero4);
                f32x4 up1 = MFMA16(a3, epsb[1], zero4);
                const float4 bb = *reinterpret_cast<const float4*>(
                    biasf + 256 + 16 * m + 4 * q);
                #pragma unroll
                for (int i = 0; i < 4; ++i) {
                    float bi = (i == 0) ? bb.x : (i == 1) ? bb.y
                              : (i == 2) ? bb.z : bb.w;
                    float h0 = ftanh(a0[i] + bi);
                    float h1v = ftanh(a1[i] + bi);
                    h3p0[sub * 4 + i] = (_Float16)h0;
                    h3p1[sub * 4 + i] = (_Float16)h1v;
                    u3p[mp][0][sub * 4 + i] =
                        (_Float16)(os * up0[i] * (1.f - h0 * h0));
                    u3p[mp][1][sub * 4 + i] =
                        (_Float16)(os * up1[i] * (1.f - h1v * h1v));
                }
            }
            f16x8 Af = lds_a8(WOUTT + l15 * 132 + mp * 32 + 8 * q);
            f0 = MFMA32(Af, h3p0, f0);
            f1 = MFMA32(Af, h3p1, f1);
        }
        // stage f to LDS now (frees f0/f1 before bwd phase)
        if (q == 0) {
            outst[(0 * 16 + l15) * 3 + 0] = (f0[0] + bo0) * os;
            outst[(0 * 16 + l15) * 3 + 1] = (f0[1] + bo1) * os;
            outst[(0 * 16 + l15) * 3 + 2] = (f0[2] + bo2) * os;
            outst[(1 * 16 + l15) * 3 + 0] = (f1[0] + bo0) * os;
            outst[(1 * 16 + l15) * 3 + 1] = (f1[1] + bo1) * os;
            outst[(1 * 16 + l15) * 3 + 2] = (f1[2] + bo2) * os;
        }

        // ================= bwd3: U2 = (W_h2 @ U3) * (1-h2^2) ===============
        #pragma unroll
        for (int m = 0; m < 8; ++m) {
            f32x4 a0 = zero4, a1 = zero4;
            #pragma unroll
            for (int a = 0; a < 4; ++a) {
                f16x8 A = lds_a8(WB2 + (16 * m + l15) * 132 + a * 32 + 8 * q);
                a0 = MFMA32(A, u3p[a][0], a0);
                a1 = MFMA32(A, u3p[a][1], a1);
            }
            #pragma unroll
            for (int i = 0; i < 4; ++i) {
                float h0 = (float)h2p[m >> 1][0][(m & 1) * 4 + i];
                float h1v = (float)h2p[m >> 1][1][(m & 1) * 4 + i];
                h2p[m >> 1][0][(m & 1) * 4 + i] =
                    (_Float16)(a0[i] * (1.f - h0 * h0));      // h2p becomes u2
                h2p[m >> 1][1][(m & 1) * 4 + i] =
                    (_Float16)(a1[i] * (1.f - h1v * h1v));
            }
        }

        // ==== bwd2 + fused gz: U1 streamed in m-pairs into gz accumulator ==
        f32x4 g0 = zero4, g1 = zero4;
        #pragma unroll
        for (int mp = 0; mp < 4; ++mp) {
            f16x8 u1p0, u1p1;
            #pragma unroll
            for (int sub = 0; sub < 2; ++sub) {
                const int m = 2 * mp + sub;
                f32x4 a0 = zero4, a1 = zero4;
                #pragma unroll
                for (int a = 0; a < 4; ++a) {
                    f16x8 A = lds_a8(WB1 + (16 * m + l15) * 132 + a * 32 + 8 * q);
                    a0 = MFMA32(A, h2p[a][0], a0);
                    a1 = MFMA32(A, h2p[a][1], a1);
                }
                #pragma unroll
                for (int i = 0; i < 4; ++i) {
                    float h0 = (float)h1p[mp][0][sub * 4 + i];
                    float h1v = (float)h1p[mp][1][sub * 4 + i];
                    u1p0[sub * 4 + i] = (_Float16)(a0[i] * (1.f - h0 * h0));
                    u1p1[sub * 4 + i] = (_Float16)(a1[i] * (1.f - h1v * h1v));
                }
            }
            f16x8 Ag = lds_a8(WIN3 + l15 * 132 + mp * 32 + 8 * q);
            g0 = MFMA32(Ag, u1p0, g0);
            g1 = MFMA32(Ag, u1p1, g1);
        }
        if (q == 0) {   // 16-lane coalesced dword stores, direct
            out_nd[gb + l15] =
                -(g0[0] * ee[0][0] + g0[1] * ee[0][1] + g0[2] * ee[0][2]);
            out_nd[gb + 16 + l15] =
                -(g1[0] * ee[1][0] + g1[1] * ee[1][1] + g1[2] * ee[1][2]);
        }

        // ---- dense f stores from LDS staging (in-order same-wave DS)
        if (lane < 24) {
            float4 v = *reinterpret_cast<const float4*>(outst + lane * 4);
            *reinterpret_cast<float4*>(out_f + (size_t)gb * 3 + lane * 4) = v;
        }
    }
}

extern "C" void kernel_launch(void* const* d_in, const int* in_sizes, int n_in,
                              void* d_out, int out_size, void* d_ws, size_t ws_size,
                              hipStream_t stream) {
    const float* t_p   = (const float*)d_in[0];
    const float* z     = (const float*)d_in[1];
    // d_in[2] = logp (unused)
    const float* ctx   = (const float*)d_in[3];
    const float* eps   = (const float*)d_in[4];
    const float* W_in  = (const float*)d_in[5];
    const float* b_in  = (const float*)d_in[6];
    const float* W_h1  = (const float*)d_in[7];
    const float* b_h1  = (const float*)d_in[8];
    const float* W_h2  = (const float*)d_in[9];
    const float* b_h2  = (const float*)d_in[10];
    const float* W_out = (const float*)d_in[11];
    const float* b_out = (const float*)d_in[12];
    const float* os_p  = (const float*)d_in[13];
    _Float16* ws = (_Float16*)d_ws;
    float* out = (float*)d_out;

    static bool attr_set = false;
    if (!attr_set) {
        (void)hipFuncSetAttribute((const void*)fused_kernel,
                                  hipFuncAttributeMaxDynamicSharedMemorySize,
                                  LDS_BYTES);
        attr_set = true;
    }

    prep_kernel<<<(PREP_N + 255) / 256, 256, 0, stream>>>(
        W_in, W_h1, W_h2, W_out, b_in, b_h1, b_h2, ws);
    fused_kernel<<<GRID, 512, LDS_BYTES, stream>>>(
        t_p, z, ctx, eps, b_out, os_p, ws, out);
}